// Round 1
// baseline (845.277 us; speedup 1.0000x reference)
//
#include <hip/hip_runtime.h>

// SGC layer: N=100000 nodes, E=1600000 edges, D_IN=32, D_OUT=64, 2 hops,
// per-hop cut of the 160000 lowest-cosine edges (exact top-k w/ index ties).

constexpr int NN   = 100000;
constexpr int NE   = 1600000;
constexpr int DI   = 32;
constexpr int DO   = 64;
constexpr int KCUT = 160000;

// ---------------- degree / norm ----------------

__global__ void k_zero_u32(unsigned* p, int n) {
  int i = blockIdx.x * blockDim.x + threadIdx.x;
  if (i < n) p[i] = 0u;
}

__global__ void k_deg(const int* __restrict__ dst, unsigned* __restrict__ degi) {
  int e = blockIdx.x * blockDim.x + threadIdx.x;
  if (e < NE) atomicAdd(&degi[dst[e]], 1u);
}

__global__ void k_norm(const unsigned* __restrict__ degi, float* __restrict__ nrm) {
  int i = blockIdx.x * blockDim.x + threadIdx.x;
  if (i < NN) {
    unsigned d = degi[i]; if (d < 1u) d = 1u;
    nrm[i] = (float)(1.0 / sqrt((double)d));   // == pow(deg, -0.5)
  }
}

// ---------------- prefix sum (rowptr) ----------------

__global__ void k_psum_a(const unsigned* __restrict__ degi, unsigned* __restrict__ bsum) {
  __shared__ unsigned s[1024];
  int t = threadIdx.x;
  int i = blockIdx.x * 1024 + t;
  s[t] = (i < NN) ? degi[i] : 0u;
  __syncthreads();
  for (int off = 512; off > 0; off >>= 1) {
    if (t < off) s[t] += s[t + off];
    __syncthreads();
  }
  if (t == 0) bsum[blockIdx.x] = s[0];
}

__global__ void k_psum_b(unsigned* bsum, int nb, unsigned* rowptr) {
  if (threadIdx.x == 0 && blockIdx.x == 0) {
    unsigned run = 0;
    for (int b = 0; b < nb; b++) { unsigned v = bsum[b]; bsum[b] = run; run += v; }
    rowptr[NN] = run;   // == NE
  }
}

__global__ void k_psum_c(const unsigned* __restrict__ degi, const unsigned* __restrict__ bsum,
                         unsigned* __restrict__ rowptr, unsigned* __restrict__ fill) {
  __shared__ unsigned s[1024];
  int t = threadIdx.x;
  int i = blockIdx.x * 1024 + t;
  unsigned v = (i < NN) ? degi[i] : 0u;
  s[t] = v; __syncthreads();
  for (int off = 1; off < 1024; off <<= 1) {
    unsigned x = (t >= off) ? s[t - off] : 0u;
    __syncthreads();
    s[t] += x;
    __syncthreads();
  }
  if (i < NN) {
    unsigned excl = bsum[blockIdx.x] + s[t] - v;
    rowptr[i] = excl;
    fill[i]   = excl;
  }
}

__global__ void k_scatter(const int* __restrict__ src, const int* __restrict__ dst,
                          unsigned* __restrict__ fill, unsigned* __restrict__ csr_src,
                          unsigned* __restrict__ csr_eid) {
  int e = blockIdx.x * blockDim.x + threadIdx.x;
  if (e < NE) {
    int d = dst[e];
    unsigned p = atomicAdd(&fill[d], 1u);
    csr_src[p] = (unsigned)src[e];
    csr_eid[p] = (unsigned)e;
  }
}

// ---------------- per-hop kernels ----------------

// 8 nodes per 256-thread block; lane = feature dim
__global__ void k_rownorm(const float* __restrict__ h, const float* __restrict__ nrm,
                          float* __restrict__ nh, float* __restrict__ hn) {
  int lane = threadIdx.x & 31;
  int n = blockIdx.x * 8 + (threadIdx.x >> 5);
  float v = h[n * DI + lane];
  double sq = (double)v * (double)v;
  #pragma unroll
  for (int m = 16; m > 0; m >>= 1) sq += __shfl_xor(sq, m, 32);
  double den = sqrt(sq);
  if (den < 1e-12) den = 1e-12;
  nh[n * DI + lane] = (float)((double)v / den);
  hn[n * DI + lane] = v * nrm[n];
}

__global__ void k_cos(const unsigned* __restrict__ csr_src, const unsigned* __restrict__ csr_eid,
                      const int* __restrict__ dst, const float* __restrict__ nh,
                      unsigned long long* __restrict__ key) {
  int j = blockIdx.x * blockDim.x + threadIdx.x;
  if (j >= NE) return;
  unsigned s = csr_src[j];
  unsigned e = csr_eid[j];
  unsigned d = (unsigned)dst[e];
  const float4* a = (const float4*)(nh + (size_t)s * DI);
  const float4* b = (const float4*)(nh + (size_t)d * DI);
  double acc = 0.0;
  #pragma unroll
  for (int q = 0; q < 8; q++) {
    float4 x = a[q], y = b[q];
    acc += (double)(x.x * y.x) + (double)(x.y * y.y)
         + (double)(x.z * y.z) + (double)(x.w * y.w);
  }
  float c = (float)acc;
  unsigned u = __float_as_uint(c);
  u = (u & 0x80000000u) ? ~u : (u | 0x80000000u);   // monotone float->uint
  key[j] = ((unsigned long long)u << 32) | (unsigned long long)e;
}

// ---------------- radix select (K-th smallest 64-bit key) ----------------
// state[0] = prefix (becomes the K-th smallest key), state[1] = k remaining

__global__ void k_radix_init(unsigned* hist, unsigned long long* state) {
  int t = threadIdx.x;
  hist[t] = 0u;
  if (t == 0) { state[0] = 0ull; state[1] = (unsigned long long)KCUT; }
}

__global__ void k_radix_hist(const unsigned long long* __restrict__ key,
                             const unsigned long long* __restrict__ state,
                             unsigned* __restrict__ hist, int b) {
  __shared__ unsigned lh[256];
  int t = threadIdx.x;
  lh[t] = 0u; __syncthreads();
  unsigned long long pref = state[0];
  int stride = gridDim.x * blockDim.x;
  for (int j = blockIdx.x * blockDim.x + t; j < NE; j += stride) {
    unsigned long long k = key[j];
    bool ok = (b == 7) || (((k ^ pref) >> (8 * b + 8)) == 0ull);
    if (ok) atomicAdd(&lh[(unsigned)((k >> (8 * b)) & 255ull)], 1u);
  }
  __syncthreads();
  if (lh[t]) atomicAdd(&hist[t], lh[t]);
}

__global__ void k_radix_select(unsigned* hist, unsigned long long* state, int b) {
  __shared__ unsigned s[256];
  int t = threadIdx.x;
  unsigned v = hist[t];
  unsigned krem = (unsigned)state[1];        // read before any write
  s[t] = v; __syncthreads();
  for (int off = 1; off < 256; off <<= 1) {
    unsigned x = (t >= off) ? s[t - off] : 0u;
    __syncthreads();
    s[t] += x;
    __syncthreads();
  }
  unsigned incl = s[t];
  unsigned excl = incl - v;
  if (incl >= krem && excl < krem) {         // exactly one thread
    state[0] = state[0] | ((unsigned long long)t << (8 * b));
    state[1] = (unsigned long long)(krem - excl);
  }
  hist[t] = 0u;                              // ready for next round
}

// ---------------- propagate (CSR, no float atomics) ----------------

__global__ void k_prop(const unsigned* __restrict__ rowptr, const unsigned* __restrict__ csr_src,
                       const unsigned long long* __restrict__ key,
                       const unsigned long long* __restrict__ state,
                       const float* __restrict__ hn, const float* __restrict__ nrm,
                       float* __restrict__ hout) {
  int lane = threadIdx.x & 31;
  int n = blockIdx.x * 8 + (threadIdx.x >> 5);
  unsigned long long X = state[0];           // cut iff key <= X
  unsigned j0 = rowptr[n], j1 = rowptr[n + 1];
  double acc = 0.0;
  for (unsigned j = j0; j < j1; j++) {
    if (key[j] > X) {
      unsigned s = csr_src[j];
      acc += (double)hn[s * DI + lane];
    }
  }
  float hs = (float)acc;
  hout[n * DI + lane] = hs * nrm[n];
}

// ---------------- final FC: out = h @ W^T ----------------

__global__ void k_fc(const float* __restrict__ h, const float* __restrict__ W,
                     float* __restrict__ out) {
  __shared__ float Wt[DI * 65];   // Wt[d][o], padded stride 65 to kill bank conflicts
  __shared__ float hs[4 * DI];
  int t = threadIdx.x;
  #pragma unroll
  for (int i = 0; i < 8; i++) {
    int idx = t + i * 256;                 // idx = o*32 + d
    Wt[(idx & 31) * 65 + (idx >> 5)] = W[idx];
  }
  int n0 = blockIdx.x * 4;
  if (t < 128) hs[t] = h[n0 * DI + t];
  __syncthreads();
  int o = t & 63, nl = t >> 6;
  float acc = 0.f;
  #pragma unroll
  for (int d = 0; d < DI; d++) acc += hs[nl * DI + d] * Wt[d * 65 + o];
  out[(n0 + nl) * DO + o] = acc;
}

// ---------------- launch ----------------

extern "C" void kernel_launch(void* const* d_in, const int* in_sizes, int n_in,
                              void* d_out, int out_size, void* d_ws, size_t ws_size,
                              hipStream_t stream) {
  const float* feat = (const float*)d_in[0];
  const int*   src  = (const int*)d_in[1];
  const int*   dst  = (const int*)d_in[2];
  const float* W    = (const float*)d_in[3];
  float*       out  = (float*)d_out;

  // workspace layout (~66 MB), all offsets 8B-aligned
  float* bufA = (float*)d_ws;
  float* bufB = bufA + (size_t)NN * DI;
  float* bufC = bufB + (size_t)NN * DI;
  unsigned long long* key = (unsigned long long*)(bufC + (size_t)NN * DI);
  float*    nrm     = (float*)(key + NE);
  unsigned* degi    = (unsigned*)(nrm + NN);
  unsigned* rowptr  = degi + NN;             // NN+2 slots (pad keeps 8B alignment)
  unsigned* fill    = rowptr + NN + 2;
  unsigned* bsum    = fill + NN;             // 128 slots
  unsigned* csr_src = bsum + 128;
  unsigned* csr_eid = csr_src + NE;
  unsigned* hist    = csr_eid + NE;          // 256
  unsigned long long* state = (unsigned long long*)(hist + 256); // 2

  // degree + norm + CSR (edges are hop-invariant)
  k_zero_u32<<<(NN + 255) / 256, 256, 0, stream>>>(degi, NN);
  k_deg<<<NE / 256, 256, 0, stream>>>(dst, degi);
  k_norm<<<(NN + 255) / 256, 256, 0, stream>>>(degi, nrm);
  int nb = (NN + 1023) / 1024;   // 98
  k_psum_a<<<nb, 1024, 0, stream>>>(degi, bsum);
  k_psum_b<<<1, 1, 0, stream>>>(bsum, nb, rowptr);
  k_psum_c<<<nb, 1024, 0, stream>>>(degi, bsum, rowptr, fill);
  k_scatter<<<NE / 256, 256, 0, stream>>>(src, dst, fill, csr_src, csr_eid);

  // hop 0: nh=A, hn=B, out=A   |   hop 1: in=A, nh=C, hn=B, out=C
  const float* hin = feat;
  for (int hop = 0; hop < 2; hop++) {
    float* nh = (hop == 0) ? bufA : bufC;
    float* hn = bufB;
    float* ho = (hop == 0) ? bufA : bufC;
    k_rownorm<<<NN / 8, 256, 0, stream>>>(hin, nrm, nh, hn);
    k_cos<<<NE / 256, 256, 0, stream>>>(csr_src, csr_eid, dst, nh, key);
    k_radix_init<<<1, 256, 0, stream>>>(hist, state);
    for (int b = 7; b >= 0; b--) {
      k_radix_hist<<<1024, 256, 0, stream>>>(key, state, hist, b);
      k_radix_select<<<1, 256, 0, stream>>>(hist, state, b);
    }
    k_prop<<<NN / 8, 256, 0, stream>>>(rowptr, csr_src, key, state, hn, nrm, ho);
    hin = ho;
  }
  k_fc<<<NN / 4, 256, 0, stream>>>(hin, W, out);
}